// Round 5
// baseline (148.881 us; speedup 1.0000x reference)
//
#include <hip/hip_runtime.h>
#include <stdint.h>

#define NQ 64
#define ZNEAR 0.1f
#define ZFAR 1000.0f
#define FT 16   // fill tile

// ---------------- wave reductions (64-lane) ----------------
__device__ __forceinline__ float wave_min_f(float v) {
    #pragma unroll
    for (int off = 1; off < 64; off <<= 1)
        v = fminf(v, __shfl_xor(v, off, 64));
    return v;
}
__device__ __forceinline__ float wave_max_f(float v) {
    #pragma unroll
    for (int off = 1; off < 64; off <<= 1)
        v = fmaxf(v, __shfl_xor(v, off, 64));
    return v;
}

// ---------------- K1: project + pack + per-block min/max partials + payload-array zero ----------
// packed layout: bit31 = valid, bits[0:12) = x, bits[12:24) = y
__global__ void k_project(const float* __restrict__ pp, const float* __restrict__ conf,
                          const float* __restrict__ pose, const float* __restrict__ Km,
                          const int* __restrict__ hp, const int* __restrict__ wp,
                          int B, int n,
                          float* __restrict__ zbuf, unsigned* __restrict__ packed,
                          float* __restrict__ pmin, float* __restrict__ pmax, int nBlk,
                          uint4* __restrict__ pixz16, size_t nZero16) {
    int bb = blockIdx.y;
    int i = blockIdx.x * blockDim.x + threadIdx.x;
    // fused zeroing of the 5 payload images (5*pix qwords = nZero16 uint4's)
    size_t ztid = ((size_t)blockIdx.y * gridDim.x + blockIdx.x) * blockDim.x + threadIdx.x;
    size_t zstr = (size_t)gridDim.x * gridDim.y * blockDim.x;
    uint4 zz = make_uint4(0u, 0u, 0u, 0u);
    for (size_t k = ztid; k < nZero16; k += zstr) pixz16[k] = zz;

    int h = *hp, w = *wp;
    float inv_lo = INFINITY;   // neutral for min
    float inv_hi = 0.0f;       // neutral for max
    if (i < n) {
        const float* P  = pose + (size_t)bb * 16;
        const float* km = Km   + (size_t)bb * 9;
        const float* pb = pp   + (size_t)bb * 7 * n;
        float X  = pb[0 * (size_t)n + i];
        float Y  = pb[1 * (size_t)n + i];
        float Z  = pb[2 * (size_t)n + i];
        float Wc = pb[3 * (size_t)n + i];
        float pc0 = P[0] * X + P[1] * Y + P[2]  * Z + P[3]  * Wc;
        float pc1 = P[4] * X + P[5] * Y + P[6]  * Z + P[7]  * Wc;
        float pc2 = P[8] * X + P[9] * Y + P[10] * Z + P[11] * Wc;
        float z = fabsf(pc2);
        // mirror reference op order: (pc * f) / z + c
        float xc = pc0 * km[0] / z + km[2];
        float yc = pc1 * km[4] / z + km[5];
        float xr = rintf(xc);   // round-half-even, same as jnp.round
        float yr = rintf(yc);
        float cf = conf[(size_t)bb * n + i];
        bool valid = (xr >= 0.0f) && (xr <= (float)(w - 1)) &&
                     (yr >= 0.0f) && (yr <= (float)(h - 1)) &&
                     (z >= ZNEAR) && (z <= ZFAR) && (cf > 0.0f);
        unsigned px = valid ? (unsigned)(int)xr : 0u;
        unsigned py = valid ? (unsigned)(int)yr : 0u;
        size_t p = (size_t)bb * n + i;
        zbuf[p] = z;
        packed[p] = (valid ? 0x80000000u : 0u) | px | (py << 12);
        inv_lo = valid ? (1.0f / z) : (1.0f / 1e-10f);
        inv_hi = valid ? (1.0f / z) : (1.0f / 1e10f);
    }
    __shared__ float smin[4], smax[4];
    float wmin = wave_min_f(inv_lo);
    float wmax = wave_max_f(inv_hi);
    int lane = threadIdx.x & 63, wid = threadIdx.x >> 6;
    if (lane == 0) { smin[wid] = wmin; smax[wid] = wmax; }
    __syncthreads();
    if (threadIdx.x == 0) {
        pmin[(size_t)bb * nBlk + blockIdx.x] = fminf(fminf(smin[0], smin[1]), fminf(smin[2], smin[3]));
        pmax[(size_t)bb * nBlk + blockIdx.x] = fmaxf(fmaxf(smax[0], smax[1]), fmaxf(smax[2], smax[3]));
    }
}

// ---------------- K2: inline minmax fold + payload-carrying scatter ----------------
// Per valid point: 5x atomicMax64 of (key<<32)|payload to the 5 pixel images.
// key = (dq<<20)|(i+1) is unique per point, so each image independently converges to the
// SAME winner's payload (payload bits never decide between distinct points).
// Winner order == reference: dq monotone non-decreasing in 1/z => argmin-over-bins of
// stored z is the highest occupied bin; within a bin, last-written (max index) wins.
__global__ void k_scatter(const float* __restrict__ pp, const float* __restrict__ conf,
                          const float* __restrict__ zbuf, const unsigned* __restrict__ packed,
                          const float* __restrict__ pminb, const float* __restrict__ pmaxb, int nBlk,
                          const int* __restrict__ hp, const int* __restrict__ wp,
                          int B, int n, unsigned long long* __restrict__ pixw, int pixTot) {
    __shared__ float smin[4], smax[4];
    __shared__ float sdlo[8], sdhi[8];   // B <= 8
    for (int bb = 0; bb < B; ++bb) {
        float lmin = INFINITY, lmax = 0.0f;
        for (int k = threadIdx.x; k < nBlk; k += blockDim.x) {
            lmin = fminf(lmin, pminb[(size_t)bb * nBlk + k]);
            lmax = fmaxf(lmax, pmaxb[(size_t)bb * nBlk + k]);
        }
        lmin = wave_min_f(lmin);
        lmax = wave_max_f(lmax);
        int lane = threadIdx.x & 63, wid = threadIdx.x >> 6;
        if (lane == 0) { smin[wid] = lmin; smax[wid] = lmax; }
        __syncthreads();
        if (threadIdx.x == 0) {
            sdlo[bb] = fminf(fminf(smin[0], smin[1]), fminf(smin[2], smin[3]));
            sdhi[bb] = fmaxf(fmaxf(smax[0], smax[1]), fmaxf(smax[2], smax[3]));
        }
        __syncthreads();
    }
    int p = blockIdx.x * blockDim.x + threadIdx.x;
    if (p >= B * n) return;
    unsigned pk = packed[p];
    if (!(pk & 0x80000000u)) return;
    int bb = p / n;
    int i = p - bb * n;
    float z = zbuf[p];
    float inv = 1.0f / z;
    float dlo = sdlo[bb], dhi = sdhi[bb];
    int dq = (int)((inv - dlo) / (dhi - dlo) * (float)(NQ - 1));  // trunc, matches astype(int32)
    int h = *hp, w = *wp;
    int x = (int)(pk & 0xFFFu);
    int y = (int)((pk >> 12) & 0xFFFu);
    unsigned key = ((unsigned)dq << 20) | (unsigned)(i + 1);      // needs n < 2^20
    unsigned long long hi = (unsigned long long)key << 32;
    size_t pxi = (size_t)bb * h * w + (size_t)y * w + x;
    const float* pb = pp + (size_t)bb * 7 * n;
    atomicMax(&pixw[pxi],                     hi | (unsigned long long)__float_as_uint(z));
    atomicMax(&pixw[(size_t)pixTot     + pxi], hi | (unsigned long long)__float_as_uint(conf[(size_t)bb * n + i]));
    atomicMax(&pixw[2 * (size_t)pixTot + pxi], hi | (unsigned long long)__float_as_uint(pb[4 * (size_t)n + i]));
    atomicMax(&pixw[3 * (size_t)pixTot + pxi], hi | (unsigned long long)__float_as_uint(pb[5 * (size_t)n + i]));
    atomicMax(&pixw[4 * (size_t)pixTot + pxi], hi | (unsigned long long)__float_as_uint(pb[6 * (size_t)n + i]));
}

// ---------------- K3: fused resolve + BOTH hole-fill iterations, grid-stride over tiles ------
// Halo = coalesced reads of the 5 payload images at the flipped row; payload = low 32 bits
// (qword 0 => payload 0.0 == empty-pixel default for depth / max(conf,0) / rgb).
__global__ void __launch_bounds__(256, 4)
k_resfill(const unsigned long long* __restrict__ pixw,
          const float* __restrict__ filt,
          const int* __restrict__ hp, const int* __restrict__ wp,
          int B, float* __restrict__ out, int pixTot) {
    int h = *hp, w = *wp;
    int tilesX = (w + FT - 1) / FT;
    int tilesY = (h + FT - 1) / FT;
    int TPB = tilesX * tilesY;          // tiles per batch
    int T = TPB * B;
    int hw = h * w;
    int tid = threadIdx.x;

    __shared__ float s_f[72];
    __shared__ float s_in[5][20][20];
    __shared__ float s_m[5][18][18];
    if (tid < 72) s_f[tid] = filt[tid];

    for (int t = blockIdx.x; t < T; t += gridDim.x) {
        int bb = t / TPB;
        int tile = t - bb * TPB;
        int tY = tile / tilesX, tX = tile - tY * tilesX;
        int gy0 = tY * FT - 2, gx0 = tX * FT - 2;   // origin of the 20x20 halo

        for (int idx = tid; idx < 400; idx += blockDim.x) {
            int yy = idx / 20, xx = idx - yy * 20;
            int gy = gy0 + yy, gx = gx0 + xx;
            float v[5] = {0.0f, 0.0f, 0.0f, 0.0f, 0.0f};
            if (((unsigned)gy < (unsigned)h) && ((unsigned)gx < (unsigned)w)) {
                int ys = h - 1 - gy;            // flipped source row
                size_t g = (size_t)bb * hw + (size_t)ys * w + gx;
                #pragma unroll
                for (int ch = 0; ch < 5; ++ch)
                    v[ch] = __uint_as_float((unsigned)(pixw[(size_t)ch * pixTot + g] & 0xFFFFFFFFull));
            }
            #pragma unroll
            for (int ch = 0; ch < 5; ++ch) s_in[ch][yy][xx] = v[ch];
        }
        __syncthreads();

        // ---- iteration 1 at 18x18 positions (s_in coords 1..18) ----
        for (int idx = tid; idx < 324; idx += blockDim.x) {
            int py = idx / 18, px = idx - py * 18;
            int sy = py + 1, sx = px + 1;
            int gy = gy0 + sy, gx = gx0 + sx;
            bool vc = ((unsigned)gy < (unsigned)h) && ((unsigned)gx < (unsigned)w);
            float d[9];
            #pragma unroll
            for (int t9 = 0; t9 < 9; ++t9) d[t9] = s_in[0][sy + t9 / 3 - 1][sx + t9 % 3 - 1];
            float s = 0.0f;
            #pragma unroll
            for (int t9 = 0; t9 < 9; ++t9) s += d[t9];
            float dc0 = d[4];
            float ov[5];
            #pragma unroll
            for (int ch = 0; ch < 5; ++ch) ov[ch] = s_in[ch][sy][sx];
            if ((s > 0.0f) && (dc0 <= 0.0f)) {
                float prod = 1.0f;
                #pragma unroll
                for (int k = 0; k < 8; ++k) {
                    float o = 0.0f;
                    #pragma unroll
                    for (int t9 = 0; t9 < 9; ++t9) o += s_f[k * 9 + t9] * d[t9];
                    prod *= o;
                }
                if (fabsf(prod) > 1e-10f) {
                    #pragma unroll
                    for (int ch = 0; ch < 5; ++ch) {
                        float m = -INFINITY;
                        #pragma unroll
                        for (int t9 = 0; t9 < 9; ++t9) {
                            int ny = gy + t9 / 3 - 1, nx = gx + t9 % 3 - 1;
                            if (((unsigned)ny < (unsigned)h) && ((unsigned)nx < (unsigned)w))
                                m = fmaxf(m, s_in[ch][sy + t9 / 3 - 1][sx + t9 % 3 - 1]);
                        }
                        ov[ch] = m;
                    }
                }
            }
            if (!vc) { ov[0] = 0.0f; ov[1] = 0.0f; ov[2] = 0.0f; ov[3] = 0.0f; ov[4] = 0.0f; }
            #pragma unroll
            for (int ch = 0; ch < 5; ++ch) s_m[ch][py][px] = ov[ch];
        }
        __syncthreads();

        // ---- iteration 2 at own pixel (16x16) ----
        int ly = tid >> 4, lx = tid & 15;
        int gy = tY * FT + ly, gx = tX * FT + lx;
        if (((unsigned)gy < (unsigned)h) && ((unsigned)gx < (unsigned)w)) {
            int sy = ly + 1, sx = lx + 1;   // coords in s_m
            float d[9];
            #pragma unroll
            for (int t9 = 0; t9 < 9; ++t9) d[t9] = s_m[0][sy + t9 / 3 - 1][sx + t9 % 3 - 1];
            float s = 0.0f;
            #pragma unroll
            for (int t9 = 0; t9 < 9; ++t9) s += d[t9];
            float dc0 = d[4];
            float ov[5];
            #pragma unroll
            for (int ch = 0; ch < 5; ++ch) ov[ch] = s_m[ch][sy][sx];
            if ((s > 0.0f) && (dc0 <= 0.0f)) {
                float prod = 1.0f;
                #pragma unroll
                for (int k = 0; k < 8; ++k) {
                    float o = 0.0f;
                    #pragma unroll
                    for (int t9 = 0; t9 < 9; ++t9) o += s_f[k * 9 + t9] * d[t9];
                    prod *= o;
                }
                if (fabsf(prod) > 1e-10f) {
                    #pragma unroll
                    for (int ch = 0; ch < 5; ++ch) {
                        float m = -INFINITY;
                        #pragma unroll
                        for (int t9 = 0; t9 < 9; ++t9) {
                            int ny = gy + t9 / 3 - 1, nx = gx + t9 % 3 - 1;
                            if (((unsigned)ny < (unsigned)h) && ((unsigned)nx < (unsigned)w))
                                m = fmaxf(m, s_m[ch][sy + t9 / 3 - 1][sx + t9 % 3 - 1]);
                        }
                        ov[ch] = m;
                    }
                }
            }
            size_t g = (size_t)gy * w + gx;
            out[(size_t)bb * hw + g] = ov[0];
            out[(size_t)pixTot + (size_t)bb * hw + g] = ov[1];
            size_t rb = 2 * (size_t)pixTot;
            out[rb + (((size_t)bb * 3 + 0) * hw) + g] = ov[2];
            out[rb + (((size_t)bb * 3 + 1) * hw) + g] = ov[3];
            out[rb + (((size_t)bb * 3 + 2) * hw) + g] = ov[4];
        }
    }
}

static inline size_t align16(size_t x) { return (x + 15) & ~(size_t)15; }

extern "C" void kernel_launch(void* const* d_in, const int* in_sizes, int n_in,
                              void* d_out, int out_size, void* d_ws, size_t ws_size,
                              hipStream_t stream) {
    const float* pp   = (const float*)d_in[0];
    const float* conf = (const float*)d_in[1];
    const float* pose = (const float*)d_in[2];
    const float* Km   = (const float*)d_in[3];
    const float* filt = (const float*)d_in[4];
    const int*   hp   = (const int*)d_in[5];
    const int*   wp   = (const int*)d_in[6];

    int B = in_sizes[2] / 16;          // pose is [B,4,4]
    int n = in_sizes[1] / B;           // conf is [B,n]
    size_t pix = (size_t)out_size / 5; // B*h*w  (out = depth + conf + 3*rgb)
    size_t npts = (size_t)B * n;

    const int bs = 256;
    int nBlk = (n + bs - 1) / bs;

    char* ws = (char*)d_ws;
    size_t off = 0;
    unsigned long long* pixw = (unsigned long long*)(ws + off);  off = align16(off + 5 * pix * 8);
    float* zbuf   = (float*)(ws + off);        off = align16(off + npts * 4);
    unsigned* packed = (unsigned*)(ws + off);  off = align16(off + npts * 4);
    float* pminb  = (float*)(ws + off);        off = align16(off + (size_t)B * nBlk * 4);
    float* pmaxb  = (float*)(ws + off);        off = align16(off + (size_t)B * nBlk * 4);

    float* out = (float*)d_out;
    int pixI = (int)pix;
    size_t nZero16 = 5 * pix * 8 / 16;   // uint4 count (pix is even)

    dim3 gproj(nBlk, B);
    k_project<<<gproj, bs, 0, stream>>>(pp, conf, pose, Km, hp, wp, B, n,
                                        zbuf, packed, pminb, pmaxb, nBlk,
                                        (uint4*)pixw, nZero16);

    int nptsI = (int)npts;
    k_scatter<<<(nptsI + bs - 1) / bs, bs, 0, stream>>>(pp, conf, zbuf, packed,
                                                        pminb, pmaxb, nBlk,
                                                        hp, wp, B, n, pixw, pixI);

    k_resfill<<<1024, bs, 0, stream>>>(pixw, filt, hp, wp, B, out, pixI);
}

// Round 6
// 105.006 us; speedup vs baseline: 1.4178x; 1.4178x over previous
//
#include <hip/hip_runtime.h>
#include <stdint.h>

#define NQ 64
#define ZNEAR 0.1f
#define ZFAR 1000.0f
#define FT 16   // fill tile

// ---------------- wave reductions (64-lane) ----------------
__device__ __forceinline__ float wave_min_f(float v) {
    #pragma unroll
    for (int off = 1; off < 64; off <<= 1)
        v = fminf(v, __shfl_xor(v, off, 64));
    return v;
}
__device__ __forceinline__ float wave_max_f(float v) {
    #pragma unroll
    for (int off = 1; off < 64; off <<= 1)
        v = fmaxf(v, __shfl_xor(v, off, 64));
    return v;
}

// ---------------- K1: project + pack + per-block min/max partials + pixwin zero + zcr8 --------
// packed: bit31 = valid, bits[0:12) = x, bits[12:24) = y
// zcr8[p] = 32B slot {z, conf, r, g, b, -, -, -} -> ONE random cache line per winner gather.
__global__ void k_project(const float* __restrict__ pp, const float* __restrict__ conf,
                          const float* __restrict__ pose, const float* __restrict__ Km,
                          const int* __restrict__ hp, const int* __restrict__ wp,
                          int B, int n,
                          float* __restrict__ zbuf, unsigned* __restrict__ packed,
                          float4* __restrict__ zcr8,
                          float* __restrict__ pmin, float* __restrict__ pmax, int nBlk,
                          unsigned* __restrict__ pixwin, int pixTot) {
    int bb = blockIdx.y;
    int i = blockIdx.x * blockDim.x + threadIdx.x;
    // fused pixwin zeroing (grid covers B*n >= pixTot threads)
    size_t ztid = ((size_t)blockIdx.y * gridDim.x + blockIdx.x) * blockDim.x + threadIdx.x;
    if (ztid < (size_t)pixTot) pixwin[ztid] = 0u;

    int h = *hp, w = *wp;
    float inv_lo = INFINITY;   // neutral for min
    float inv_hi = 0.0f;       // neutral for max
    if (i < n) {
        const float* P  = pose + (size_t)bb * 16;
        const float* km = Km   + (size_t)bb * 9;
        const float* pb = pp   + (size_t)bb * 7 * n;
        float X  = pb[0 * (size_t)n + i];
        float Y  = pb[1 * (size_t)n + i];
        float Z  = pb[2 * (size_t)n + i];
        float Wc = pb[3 * (size_t)n + i];
        float pc0 = P[0] * X + P[1] * Y + P[2]  * Z + P[3]  * Wc;
        float pc1 = P[4] * X + P[5] * Y + P[6]  * Z + P[7]  * Wc;
        float pc2 = P[8] * X + P[9] * Y + P[10] * Z + P[11] * Wc;
        float z = fabsf(pc2);
        // mirror reference op order: (pc * f) / z + c
        float xc = pc0 * km[0] / z + km[2];
        float yc = pc1 * km[4] / z + km[5];
        float xr = rintf(xc);   // round-half-even, same as jnp.round
        float yr = rintf(yc);
        float cf = conf[(size_t)bb * n + i];
        bool valid = (xr >= 0.0f) && (xr <= (float)(w - 1)) &&
                     (yr >= 0.0f) && (yr <= (float)(h - 1)) &&
                     (z >= ZNEAR) && (z <= ZFAR) && (cf > 0.0f);
        unsigned px = valid ? (unsigned)(int)xr : 0u;
        unsigned py = valid ? (unsigned)(int)yr : 0u;
        size_t p = (size_t)bb * n + i;
        zbuf[p] = z;
        packed[p] = (valid ? 0x80000000u : 0u) | px | (py << 12);
        zcr8[2 * p]     = make_float4(z, cf, pb[4 * (size_t)n + i], pb[5 * (size_t)n + i]);
        zcr8[2 * p + 1] = make_float4(pb[6 * (size_t)n + i], 0.0f, 0.0f, 0.0f);
        inv_lo = valid ? (1.0f / z) : (1.0f / 1e-10f);
        inv_hi = valid ? (1.0f / z) : (1.0f / 1e10f);
    }
    __shared__ float smin[4], smax[4];
    float wmin = wave_min_f(inv_lo);
    float wmax = wave_max_f(inv_hi);
    int lane = threadIdx.x & 63, wid = threadIdx.x >> 6;
    if (lane == 0) { smin[wid] = wmin; smax[wid] = wmax; }
    __syncthreads();
    if (threadIdx.x == 0) {
        pmin[(size_t)bb * nBlk + blockIdx.x] = fminf(fminf(smin[0], smin[1]), fminf(smin[2], smin[3]));
        pmax[(size_t)bb * nBlk + blockIdx.x] = fmaxf(fmaxf(smax[0], smax[1]), fmaxf(smax[2], smax[3]));
    }
}

// ---------------- K2: inline minmax fold + single 32-bit atomic composite ----------------
// key = (dq<<20)|(i+1); max == (highest bin, last index). Valid because dq is monotone
// non-decreasing in 1/z (sub/div/mul/trunc all monotone): argmin-over-bins of stored z is the
// highest occupied bin; within a bin the last-written (max index) point wins.
// pixwin is 1.2 MB -> atomics stay L2-resident (R5 lesson: keep atomic footprint small).
__global__ void k_scatter(const float* __restrict__ zbuf, const unsigned* __restrict__ packed,
                          const float* __restrict__ pminb, const float* __restrict__ pmaxb, int nBlk,
                          const int* __restrict__ hp, const int* __restrict__ wp,
                          int B, int n, unsigned* __restrict__ pixwin) {
    __shared__ float smin[4], smax[4];
    __shared__ float sdlo[8], sdhi[8];   // B <= 8
    for (int bb = 0; bb < B; ++bb) {
        float lmin = INFINITY, lmax = 0.0f;
        for (int k = threadIdx.x; k < nBlk; k += blockDim.x) {
            lmin = fminf(lmin, pminb[(size_t)bb * nBlk + k]);
            lmax = fmaxf(lmax, pmaxb[(size_t)bb * nBlk + k]);
        }
        lmin = wave_min_f(lmin);
        lmax = wave_max_f(lmax);
        int lane = threadIdx.x & 63, wid = threadIdx.x >> 6;
        if (lane == 0) { smin[wid] = lmin; smax[wid] = lmax; }
        __syncthreads();
        if (threadIdx.x == 0) {
            sdlo[bb] = fminf(fminf(smin[0], smin[1]), fminf(smin[2], smin[3]));
            sdhi[bb] = fmaxf(fmaxf(smax[0], smax[1]), fmaxf(smax[2], smax[3]));
        }
        __syncthreads();
    }
    int p = blockIdx.x * blockDim.x + threadIdx.x;
    if (p >= B * n) return;
    unsigned pk = packed[p];
    if (!(pk & 0x80000000u)) return;
    int bb = p / n;
    int i = p - bb * n;
    float inv = 1.0f / zbuf[p];
    float dlo = sdlo[bb], dhi = sdhi[bb];
    int dq = (int)((inv - dlo) / (dhi - dlo) * (float)(NQ - 1));  // trunc, matches astype(int32)
    int h = *hp, w = *wp;
    int x = (int)(pk & 0xFFFu);
    int y = (int)((pk >> 12) & 0xFFFu);
    unsigned key = ((unsigned)dq << 20) | (unsigned)(i + 1);      // needs n < 2^20
    atomicMax(&pixwin[(size_t)bb * h * w + (size_t)y * w + x], key);
}

// ---------------- K3: fused resolve + BOTH hole-fill iterations, grid-stride over tiles ------
// Halo resolves winners from pixwin at the flipped row; one 32B zcr8 line per winner.
__global__ void __launch_bounds__(256, 4)
k_resfill(const float4* __restrict__ zcr8, const unsigned* __restrict__ pixwin,
          const float* __restrict__ filt,
          const int* __restrict__ hp, const int* __restrict__ wp,
          int B, int n, float* __restrict__ out, int pixTot) {
    int h = *hp, w = *wp;
    int tilesX = (w + FT - 1) / FT;
    int tilesY = (h + FT - 1) / FT;
    int TPB = tilesX * tilesY;          // tiles per batch
    int T = TPB * B;
    int hw = h * w;
    int tid = threadIdx.x;

    __shared__ float s_f[72];
    __shared__ float s_in[5][20][20];
    __shared__ float s_m[5][18][18];
    if (tid < 72) s_f[tid] = filt[tid];

    for (int t = blockIdx.x; t < T; t += gridDim.x) {
        int bb = t / TPB;
        int tile = t - bb * TPB;
        int tY = tile / tilesX, tX = tile - tY * tilesX;
        int gy0 = tY * FT - 2, gx0 = tX * FT - 2;   // origin of the 20x20 halo

        for (int idx = tid; idx < 400; idx += blockDim.x) {
            int yy = idx / 20, xx = idx - yy * 20;
            int gy = gy0 + yy, gx = gx0 + xx;
            float v0 = 0.0f, v1 = 0.0f, v2 = 0.0f, v3 = 0.0f, v4 = 0.0f;
            if (((unsigned)gy < (unsigned)h) && ((unsigned)gx < (unsigned)w)) {
                int ys = h - 1 - gy;            // flipped source row
                unsigned key = pixwin[(size_t)bb * hw + (size_t)ys * w + gx];
                if (key) {
                    int i = (int)(key & 0xFFFFFu) - 1;
                    size_t p = (size_t)bb * n + i;
                    float4 a = zcr8[2 * p];     // {z, conf, r, g}
                    float4 c = zcr8[2 * p + 1]; // {b, -, -, -}  same 32B line
                    v0 = a.x; v1 = a.y; v2 = a.z; v3 = a.w; v4 = c.x;
                }
            }
            s_in[0][yy][xx] = v0;   // zero outside == conv 'SAME' pad; empty pixel defaults 0
            s_in[1][yy][xx] = v1;
            s_in[2][yy][xx] = v2;
            s_in[3][yy][xx] = v3;
            s_in[4][yy][xx] = v4;
        }
        __syncthreads();

        // ---- iteration 1 at 18x18 positions (s_in coords 1..18) ----
        for (int idx = tid; idx < 324; idx += blockDim.x) {
            int py = idx / 18, px = idx - py * 18;
            int sy = py + 1, sx = px + 1;
            int gy = gy0 + sy, gx = gx0 + sx;
            bool vc = ((unsigned)gy < (unsigned)h) && ((unsigned)gx < (unsigned)w);
            float d[9];
            #pragma unroll
            for (int t9 = 0; t9 < 9; ++t9) d[t9] = s_in[0][sy + t9 / 3 - 1][sx + t9 % 3 - 1];
            float s = 0.0f;
            #pragma unroll
            for (int t9 = 0; t9 < 9; ++t9) s += d[t9];
            float dc0 = d[4];
            float ov[5];
            #pragma unroll
            for (int ch = 0; ch < 5; ++ch) ov[ch] = s_in[ch][sy][sx];
            if ((s > 0.0f) && (dc0 <= 0.0f)) {
                float prod = 1.0f;
                #pragma unroll
                for (int k = 0; k < 8; ++k) {
                    float o = 0.0f;
                    #pragma unroll
                    for (int t9 = 0; t9 < 9; ++t9) o += s_f[k * 9 + t9] * d[t9];
                    prod *= o;
                }
                if (fabsf(prod) > 1e-10f) {
                    #pragma unroll
                    for (int ch = 0; ch < 5; ++ch) {
                        float m = -INFINITY;
                        #pragma unroll
                        for (int t9 = 0; t9 < 9; ++t9) {
                            int ny = gy + t9 / 3 - 1, nx = gx + t9 % 3 - 1;
                            if (((unsigned)ny < (unsigned)h) && ((unsigned)nx < (unsigned)w))
                                m = fmaxf(m, s_in[ch][sy + t9 / 3 - 1][sx + t9 % 3 - 1]);
                        }
                        ov[ch] = m;
                    }
                }
            }
            if (!vc) { ov[0] = 0.0f; ov[1] = 0.0f; ov[2] = 0.0f; ov[3] = 0.0f; ov[4] = 0.0f; }
            #pragma unroll
            for (int ch = 0; ch < 5; ++ch) s_m[ch][py][px] = ov[ch];
        }
        __syncthreads();

        // ---- iteration 2 at own pixel (16x16) ----
        int ly = tid >> 4, lx = tid & 15;
        int gy = tY * FT + ly, gx = tX * FT + lx;
        if (((unsigned)gy < (unsigned)h) && ((unsigned)gx < (unsigned)w)) {
            int sy = ly + 1, sx = lx + 1;   // coords in s_m
            float d[9];
            #pragma unroll
            for (int t9 = 0; t9 < 9; ++t9) d[t9] = s_m[0][sy + t9 / 3 - 1][sx + t9 % 3 - 1];
            float s = 0.0f;
            #pragma unroll
            for (int t9 = 0; t9 < 9; ++t9) s += d[t9];
            float dc0 = d[4];
            float ov[5];
            #pragma unroll
            for (int ch = 0; ch < 5; ++ch) ov[ch] = s_m[ch][sy][sx];
            if ((s > 0.0f) && (dc0 <= 0.0f)) {
                float prod = 1.0f;
                #pragma unroll
                for (int k = 0; k < 8; ++k) {
                    float o = 0.0f;
                    #pragma unroll
                    for (int t9 = 0; t9 < 9; ++t9) o += s_f[k * 9 + t9] * d[t9];
                    prod *= o;
                }
                if (fabsf(prod) > 1e-10f) {
                    #pragma unroll
                    for (int ch = 0; ch < 5; ++ch) {
                        float m = -INFINITY;
                        #pragma unroll
                        for (int t9 = 0; t9 < 9; ++t9) {
                            int ny = gy + t9 / 3 - 1, nx = gx + t9 % 3 - 1;
                            if (((unsigned)ny < (unsigned)h) && ((unsigned)nx < (unsigned)w))
                                m = fmaxf(m, s_m[ch][sy + t9 / 3 - 1][sx + t9 % 3 - 1]);
                        }
                        ov[ch] = m;
                    }
                }
            }
            size_t g = (size_t)gy * w + gx;
            out[(size_t)bb * hw + g] = ov[0];
            out[(size_t)pixTot + (size_t)bb * hw + g] = ov[1];
            size_t rb = 2 * (size_t)pixTot;
            out[rb + (((size_t)bb * 3 + 0) * hw) + g] = ov[2];
            out[rb + (((size_t)bb * 3 + 1) * hw) + g] = ov[3];
            out[rb + (((size_t)bb * 3 + 2) * hw) + g] = ov[4];
        }
    }
}

static inline size_t align32(size_t x) { return (x + 31) & ~(size_t)31; }

extern "C" void kernel_launch(void* const* d_in, const int* in_sizes, int n_in,
                              void* d_out, int out_size, void* d_ws, size_t ws_size,
                              hipStream_t stream) {
    const float* pp   = (const float*)d_in[0];
    const float* conf = (const float*)d_in[1];
    const float* pose = (const float*)d_in[2];
    const float* Km   = (const float*)d_in[3];
    const float* filt = (const float*)d_in[4];
    const int*   hp   = (const int*)d_in[5];
    const int*   wp   = (const int*)d_in[6];

    int B = in_sizes[2] / 16;          // pose is [B,4,4]
    int n = in_sizes[1] / B;           // conf is [B,n]
    size_t pix = (size_t)out_size / 5; // B*h*w  (out = depth + conf + 3*rgb)
    size_t npts = (size_t)B * n;

    const int bs = 256;
    int nBlk = (n + bs - 1) / bs;

    char* ws = (char*)d_ws;
    size_t off = 0;
    unsigned* pixwin = (unsigned*)(ws + off); off = align32(off + pix * 4);
    float4* zcr8  = (float4*)(ws + off);      off = align32(off + npts * 32);
    float* zbuf   = (float*)(ws + off);       off = align32(off + npts * 4);
    unsigned* packed = (unsigned*)(ws + off); off = align32(off + npts * 4);
    float* pminb  = (float*)(ws + off);       off = align32(off + (size_t)B * nBlk * 4);
    float* pmaxb  = (float*)(ws + off);       off = align32(off + (size_t)B * nBlk * 4);

    float* out = (float*)d_out;
    int pixI = (int)pix;

    dim3 gproj(nBlk, B);
    k_project<<<gproj, bs, 0, stream>>>(pp, conf, pose, Km, hp, wp, B, n,
                                        zbuf, packed, zcr8, pminb, pmaxb, nBlk,
                                        pixwin, pixI);

    int nptsI = (int)npts;
    k_scatter<<<(nptsI + bs - 1) / bs, bs, 0, stream>>>(zbuf, packed, pminb, pmaxb, nBlk,
                                                        hp, wp, B, n, pixwin);

    k_resfill<<<1024, bs, 0, stream>>>(zcr8, pixwin, filt, hp, wp, B, n, out, pixI);
}